// Round 2
// baseline (713.170 us; speedup 1.0000x reference)
//
#include <hip/hip_runtime.h>
#include <hip/hip_bf16.h>

// DecoderBlock on MI355X (gfx950), round 1: same correctness-first bf16-MFMA pipeline
// as round 0 (never benched - broker timeout), with workspace arena compacted
// 128MB -> 72MB and Y written in-place into d_out.
// B=4, L=M=1024, DIM=1024, H=16, d=64, HID=4096. All GEMMs are A[4096,K] @ W[N,K]^T.

typedef unsigned short u16;
typedef unsigned short u16x8 __attribute__((ext_vector_type(8)));
typedef __bf16 bf16x8 __attribute__((ext_vector_type(8)));
typedef float f32x4 __attribute__((ext_vector_type(4)));

__device__ __forceinline__ u16 f2bits(float f) {
  __hip_bfloat16 h = __float2bfloat16(f);
  return __builtin_bit_cast(u16, h);
}
__device__ __forceinline__ float bits2f(u16 b) {
  return __uint_as_float(((unsigned)b) << 16);
}

__device__ __forceinline__ f32x4 mfma16(u16x8 a, u16x8 b, f32x4 c) {
  return __builtin_amdgcn_mfma_f32_16x16x32_bf16(
      __builtin_bit_cast(bf16x8, a), __builtin_bit_cast(bf16x8, b), c, 0, 0, 0);
}

// async global->LDS, 16B per lane. LDS dest must be wave-uniform base + lane*16.
__device__ __forceinline__ void gload_lds16(void* lds, const void* g) {
  __builtin_amdgcn_global_load_lds(
      (__attribute__((address_space(1))) void*)g,
      (__attribute__((address_space(3))) void*)lds, 16, 0, 0);
}

// ---------------- f32 -> bf16 convert (weights) ----------------
__global__ __launch_bounds__(256) void cvt_f2b_kernel(const float* __restrict__ in,
                                                      u16* __restrict__ out) {
  const size_t i = ((size_t)blockIdx.x * 256 + threadIdx.x) * 4;
  const float4 v = *(const float4*)(in + i);
  ushort4 o;
  o.x = f2bits(v.x); o.y = f2bits(v.y); o.z = f2bits(v.z); o.w = f2bits(v.w);
  *(ushort4*)(out + i) = o;
}

// ---------------- LayerNorm (EPS=0 per source bug), f32 in -> bf16 out ----------------
__global__ __launch_bounds__(256) void ln_kernel(const float* __restrict__ in,
                                                 const float* __restrict__ w,
                                                 u16* __restrict__ out) {
  const int row = blockIdx.x;
  const int t = threadIdx.x;
  const float4 v = ((const float4*)(in + (size_t)row * 1024))[t];
  float s = v.x + v.y + v.z + v.w;
#pragma unroll
  for (int m = 1; m < 64; m <<= 1) s += __shfl_xor(s, m);
  __shared__ float red1[4], red2[4];
  const int l = t & 63, wv = t >> 6;
  if (l == 0) red1[wv] = s;
  __syncthreads();
  const float mean = (red1[0] + red1[1] + red1[2] + red1[3]) * (1.0f / 1024.0f);
  const float d0 = v.x - mean, d1 = v.y - mean, d2 = v.z - mean, d3 = v.w - mean;
  float q = d0 * d0 + d1 * d1 + d2 * d2 + d3 * d3;
#pragma unroll
  for (int m = 1; m < 64; m <<= 1) q += __shfl_xor(q, m);
  if (l == 0) red2[wv] = q;
  __syncthreads();
  const float rs = rsqrtf((red2[0] + red2[1] + red2[2] + red2[3]) * (1.0f / 1024.0f));
  const float4 wv4 = ((const float4*)w)[t];
  ushort4 o;
  o.x = f2bits(d0 * rs * wv4.x);
  o.y = f2bits(d1 * rs * wv4.y);
  o.z = f2bits(d2 * rs * wv4.z);
  o.w = f2bits(d3 * rs * wv4.w);
  *(ushort4*)(out + (size_t)row * 1024 + t * 4) = o;
}

// ---------------- GEMM: C[m,n] = sum_k A[m,k]*B[n,k]  (both K-contiguous bf16) ------
// m97 structure: 128x128 tile, BK=32, 4 waves (2x2), 4x4 fragments each, 16x16x32 MFMA.
// EPI: 0 = bf16 out; 1 = f32 out with residual add (res may alias outp, same-idx);
//      2 = exact GELU -> bf16 out.
template <int EPI>
__global__ __launch_bounds__(256) void gemm_bt(const u16* __restrict__ A,
                                               const u16* __restrict__ B,
                                               const float* __restrict__ res,
                                               void* __restrict__ outp,
                                               int N, int K) {
  __shared__ u16 As[128 * 32];
  __shared__ u16 Bs[128 * 32];
  const int tid = threadIdx.x;
  const int l = tid & 63;
  const int w = tid >> 6;
  const int wr = w >> 1, wc = w & 1;
  const int lrow = l & 15, lg = l >> 4;
  const int bn = blockIdx.x, bm = blockIdx.y;
  const int srow = tid >> 2;          // staging row (0..63); +64 for second issue
  const int scol = (tid & 3) * 8;     // staging col (8 bf16 = 16B per lane)
  const u16* Ag = A + (size_t)bm * 128 * K + (size_t)srow * K + scol;
  const u16* Bg = B + (size_t)bn * 128 * K + (size_t)srow * K + scol;
  f32x4 acc[4][4] = {};
  for (int kt = 0; kt < K; kt += 32) {
    gload_lds16(&As[tid * 8],        Ag + kt);
    gload_lds16(&As[2048 + tid * 8], Ag + (size_t)64 * K + kt);
    gload_lds16(&Bs[tid * 8],        Bg + kt);
    gload_lds16(&Bs[2048 + tid * 8], Bg + (size_t)64 * K + kt);
    __syncthreads();   // drains vmcnt -> tiles visible
    u16x8 a[4], b[4];
#pragma unroll
    for (int i = 0; i < 4; ++i)
      a[i] = *(const u16x8*)&As[(wr * 64 + i * 16 + lrow) * 32 + lg * 8];
#pragma unroll
    for (int j = 0; j < 4; ++j)
      b[j] = *(const u16x8*)&Bs[(wc * 64 + j * 16 + lrow) * 32 + lg * 8];
#pragma unroll
    for (int i = 0; i < 4; ++i)
#pragma unroll
      for (int j = 0; j < 4; ++j)
        acc[i][j] = mfma16(a[i], b[j], acc[i][j]);
    __syncthreads();
  }
  // C/D layout (verified m89/m91): col = lane&15, row = (lane>>4)*4 + reg
#pragma unroll
  for (int i = 0; i < 4; ++i) {
#pragma unroll
    for (int j = 0; j < 4; ++j) {
      const int col = bn * 128 + wc * 64 + j * 16 + lrow;
#pragma unroll
      for (int r = 0; r < 4; ++r) {
        const int row = bm * 128 + wr * 64 + i * 16 + lg * 4 + r;
        const size_t idx = (size_t)row * N + col;
        float v = acc[i][j][r];
        if (EPI == 0) {
          ((u16*)outp)[idx] = f2bits(v);
        } else if (EPI == 1) {
          ((float*)outp)[idx] = res[idx] + v;
        } else {
          float g = 0.5f * v * (1.0f + erff(v * 0.70710678118654752f));
          ((u16*)outp)[idx] = f2bits(g);
        }
      }
    }
  }
}

// ---------------- Flash attention (all-true mask), bf16 in/out --------------------
// Grid: (L/64, B*H). 4 waves x 16 q-rows. K/V tiles of 64 staged in LDS (V transposed).
__global__ __launch_bounds__(256) void attn_kernel(const u16* __restrict__ qb,
                                                   const u16* __restrict__ kb,
                                                   const u16* __restrict__ vb,
                                                   u16* __restrict__ ob,
                                                   int qs, int kstr, int vs, int os,
                                                   int H_, int M, float scale) {
  __shared__ u16 Ks[64 * 64];        // [m][d]
  __shared__ u16 Vt[64 * 64];        // [d][m]
  __shared__ u16 Ps[4][16 * 64];     // per-wave P[q][m]
  const int tid = threadIdx.x;
  const int l = tid & 63, w = tid >> 6;
  const int lrow = l & 15, lg = l >> 4;
  const int bh = blockIdx.y, qt = blockIdx.x;
  const int b = bh / H_, h = bh % H_;
  const u16* qp = qb + (size_t)b * 1024 * qs + h * 64;
  const u16* kp = kb + (size_t)b * M * kstr + h * 64;
  const u16* vp = vb + (size_t)b * M * vs + h * 64;
  // Q fragments, pre-scaled by 1/8 (power of 2 -> exact in bf16)
  u16x8 aq[2];
  {
    const u16* qrow = qp + (size_t)(qt * 64 + w * 16 + lrow) * qs;
#pragma unroll
    for (int ksI = 0; ksI < 2; ++ksI) {
      u16x8 tq = *(const u16x8*)(qrow + ksI * 32 + lg * 8);
#pragma unroll
      for (int j = 0; j < 8; ++j) tq[j] = f2bits(bits2f(tq[j]) * scale);
      aq[ksI] = tq;
    }
  }
  f32x4 oacc[4] = {};
  float mrow[4], lsum[4];
#pragma unroll
  for (int r = 0; r < 4; ++r) { mrow[r] = -3.0e38f; lsum[r] = 0.0f; }
  const int srow = tid >> 3, scol = (tid & 7) * 8;
  for (int mt = 0; mt < M; mt += 64) {
    gload_lds16(&Ks[tid * 8],        kp + (size_t)(mt + srow) * kstr + scol);
    gload_lds16(&Ks[2048 + tid * 8], kp + (size_t)(mt + 32 + srow) * kstr + scol);
#pragma unroll
    for (int ii = 0; ii < 2; ++ii) {     // V transpose through registers
      const int r0 = srow + ii * 32;
      u16x8 tv = *(const u16x8*)(vp + (size_t)(mt + r0) * vs + scol);
#pragma unroll
      for (int j = 0; j < 8; ++j) Vt[(scol + j) * 64 + r0] = tv[j];
    }
    __syncthreads();
    // S = (Q*scale) K^T : 16 x 64
    f32x4 sacc[4] = {};
#pragma unroll
    for (int nt = 0; nt < 4; ++nt)
#pragma unroll
      for (int ksI = 0; ksI < 2; ++ksI) {
        u16x8 bk = *(const u16x8*)&Ks[(nt * 16 + lrow) * 64 + ksI * 32 + lg * 8];
        sacc[nt] = mfma16(aq[ksI], bk, sacc[nt]);
      }
    // online softmax: lane owns rows lg*4+r; reduce over 16-lane groups (bits 0..3)
    float alpha[4];
#pragma unroll
    for (int r = 0; r < 4; ++r) {
      float pm = fmaxf(fmaxf(sacc[0][r], sacc[1][r]), fmaxf(sacc[2][r], sacc[3][r]));
      pm = fmaxf(pm, __shfl_xor(pm, 1));
      pm = fmaxf(pm, __shfl_xor(pm, 2));
      pm = fmaxf(pm, __shfl_xor(pm, 4));
      pm = fmaxf(pm, __shfl_xor(pm, 8));
      const float nm = fmaxf(mrow[r], pm);
      alpha[r] = __expf(mrow[r] - nm);
      mrow[r] = nm;
    }
    float rsum[4] = {0.f, 0.f, 0.f, 0.f};
#pragma unroll
    for (int nt = 0; nt < 4; ++nt)
#pragma unroll
      for (int r = 0; r < 4; ++r) {
        const float p = __expf(sacc[nt][r] - mrow[r]);
        sacc[nt][r] = p;
        rsum[r] += p;
      }
#pragma unroll
    for (int r = 0; r < 4; ++r) {
      float rsv = rsum[r];
      rsv += __shfl_xor(rsv, 1); rsv += __shfl_xor(rsv, 2);
      rsv += __shfl_xor(rsv, 4); rsv += __shfl_xor(rsv, 8);
      lsum[r] = lsum[r] * alpha[r] + rsv;
    }
    // P -> per-wave LDS (layout change for PV A-fragments)
#pragma unroll
    for (int nt = 0; nt < 4; ++nt)
#pragma unroll
      for (int r = 0; r < 4; ++r)
        Ps[w][(lg * 4 + r) * 64 + nt * 16 + lrow] = f2bits(sacc[nt][r]);
#pragma unroll
    for (int nt = 0; nt < 4; ++nt)
#pragma unroll
      for (int r = 0; r < 4; ++r)
        oacc[nt][r] *= alpha[r];
    u16x8 pa[2];
#pragma unroll
    for (int ksI = 0; ksI < 2; ++ksI)
      pa[ksI] = *(const u16x8*)&Ps[w][lrow * 64 + ksI * 32 + lg * 8];
#pragma unroll
    for (int nt = 0; nt < 4; ++nt)
#pragma unroll
      for (int ksI = 0; ksI < 2; ++ksI) {
        u16x8 bv = *(const u16x8*)&Vt[(nt * 16 + lrow) * 64 + ksI * 32 + lg * 8];
        oacc[nt] = mfma16(pa[ksI], bv, oacc[nt]);
      }
    __syncthreads();
  }
  // out[b, l, h*64+d] = O / l   (merged heads)
#pragma unroll
  for (int nt = 0; nt < 4; ++nt)
#pragma unroll
    for (int r = 0; r < 4; ++r) {
      const int row = qt * 64 + w * 16 + lg * 4 + r;
      const float v = oacc[nt][r] / lsum[r];
      ob[((size_t)b * 1024 + row) * os + h * 64 + nt * 16 + lrow] = f2bits(v);
    }
}

// ------------------------------- driver -------------------------------------------
extern "C" void kernel_launch(void* const* d_in, const int* in_sizes, int n_in,
                              void* d_out, int out_size, void* d_ws, size_t ws_size,
                              hipStream_t stream) {
  (void)in_sizes; (void)n_in; (void)out_size; (void)ws_size;
  const float* x    = (const float*)d_in[0];
  const float* ctx  = (const float*)d_in[1];
  const float* wqkv = (const float*)d_in[2];
  const float* wsa  = (const float*)d_in[3];
  const float* wq   = (const float*)d_in[4];
  const float* wkv  = (const float*)d_in[5];
  const float* wxa  = (const float*)d_in[6];
  const float* wm1  = (const float*)d_in[7];
  const float* wm2  = (const float*)d_in[8];
  const float* ln1  = (const float*)d_in[9];
  const float* lnq  = (const float*)d_in[10];
  const float* lnc  = (const float*)d_in[11];
  const float* ln2  = (const float*)d_in[12];
  float* out = (float*)d_out;
  char* ws = (char*)d_ws;
  const size_t MB = 1024 * 1024;
  // Arena, 72MB peak, lifetime-aliased:
  //  [0,8)    wscr   per-GEMM bf16 weight scratch (GEMMs serialized on stream)
  //  [8,16)   Xn -> Yn -> Zn (disjoint lifetimes)
  //  [16,48)  qkv (24MB, dead after attn1) -> {Cn [16,24), kvx [24,40), xatt [40,48)}
  //           -> h1 (32MB, all prior dead by MLP)
  //  [48,56)  attnb (dead after sa-proj) -> qx
  //  [56,72)  Xf (f32, dead after xa-proj)
  //  Y lives in d_out (in-place residual in final GEMM).
  u16*   wscr  = (u16*)(ws);
  u16*   Xn    = (u16*)(ws + 8 * MB);
  u16*   qkv   = (u16*)(ws + 16 * MB);
  u16*   attnb = (u16*)(ws + 48 * MB);
  float* Xf    = (float*)(ws + 56 * MB);
  u16*   Yn    = Xn;
  u16*   Cn    = (u16*)(ws + 16 * MB);
  u16*   qx    = attnb;
  u16*   kvx   = (u16*)(ws + 24 * MB);
  u16*   xatt  = (u16*)(ws + 40 * MB);
  u16*   Zn    = Xn;
  u16*   h1    = qkv;

  const dim3 blk(256);
  // self-attention branch
  ln_kernel<<<4096, blk, 0, stream>>>(x, ln1, Xn);
  cvt_f2b_kernel<<<3 * 1024, blk, 0, stream>>>(wqkv, wscr);
  gemm_bt<0><<<dim3(24, 32), blk, 0, stream>>>(Xn, wscr, nullptr, qkv, 3072, 1024);
  attn_kernel<<<dim3(16, 64), blk, 0, stream>>>(qkv, qkv + 1024, qkv + 2048, attnb,
                                                3072, 3072, 3072, 1024, 16, 1024, 0.125f);
  cvt_f2b_kernel<<<1024, blk, 0, stream>>>(wsa, wscr);
  gemm_bt<1><<<dim3(8, 32), blk, 0, stream>>>(attnb, wscr, x, Xf, 1024, 1024);
  // cross-attention branch
  ln_kernel<<<4096, blk, 0, stream>>>(Xf, lnq, Yn);
  ln_kernel<<<4096, blk, 0, stream>>>(ctx, lnc, Cn);
  cvt_f2b_kernel<<<1024, blk, 0, stream>>>(wq, wscr);
  gemm_bt<0><<<dim3(8, 32), blk, 0, stream>>>(Yn, wscr, nullptr, qx, 1024, 1024);
  cvt_f2b_kernel<<<2 * 1024, blk, 0, stream>>>(wkv, wscr);
  gemm_bt<0><<<dim3(16, 32), blk, 0, stream>>>(Cn, wscr, nullptr, kvx, 2048, 1024);
  attn_kernel<<<dim3(16, 64), blk, 0, stream>>>(qx, kvx, kvx + 1024, xatt,
                                                1024, 2048, 2048, 1024, 16, 1024, 0.125f);
  cvt_f2b_kernel<<<1024, blk, 0, stream>>>(wxa, wscr);
  gemm_bt<1><<<dim3(8, 32), blk, 0, stream>>>(xatt, wscr, Xf, out, 1024, 1024);
  // MLP (Y == out; final GEMM does in-place residual)
  ln_kernel<<<4096, blk, 0, stream>>>(out, ln2, Zn);
  cvt_f2b_kernel<<<4 * 1024, blk, 0, stream>>>(wm1, wscr);
  gemm_bt<2><<<dim3(32, 32), blk, 0, stream>>>(Zn, wscr, nullptr, h1, 4096, 1024);
  cvt_f2b_kernel<<<4 * 1024, blk, 0, stream>>>(wm2, wscr);
  gemm_bt<1><<<dim3(8, 32), blk, 0, stream>>>(h1, wscr, out, out, 1024, 4096);
}

// Round 5
// 576.181 us; speedup vs baseline: 1.2378x; 1.2378x over previous
//
#include <hip/hip_runtime.h>
#include <hip/hip_bf16.h>

// DecoderBlock on MI355X (gfx950), round 4 = round 2/3 resubmitted (broker timeouts,
// never benched). Changes vs round 1 (713us, passed):
//  - GEMM: 2-phase double-buffered pipeline (T3-minimum recipe), BK=64,
//    256x256/8-wave tile for N>=2048, 128x128/4-wave for N=1024; both-sides
//    XOR slot swizzle (linear LDS dest + inverse-swizzled global source, m201/m231
//    pattern) for conflict-free ds_read_b128; bijective XCD swizzle (m204); setprio.
//  - Attention: K staged with pre-swizzled global source (2-way instead of 16-way
//    bank conflict on QK^T reads); Vt/Ps row stride padded 64->72 u16.
// B=4, L=M=1024, DIM=1024, H=16, d=64, HID=4096. All GEMMs A[4096,K] @ W[N,K]^T.

typedef unsigned short u16;
typedef unsigned short u16x8 __attribute__((ext_vector_type(8)));
typedef __bf16 bf16x8 __attribute__((ext_vector_type(8)));
typedef float f32x4 __attribute__((ext_vector_type(4)));

__device__ __forceinline__ u16 f2bits(float f) {
  __hip_bfloat16 h = __float2bfloat16(f);
  return __builtin_bit_cast(u16, h);
}
__device__ __forceinline__ float bits2f(u16 b) {
  return __uint_as_float(((unsigned)b) << 16);
}

__device__ __forceinline__ f32x4 mfma16(u16x8 a, u16x8 b, f32x4 c) {
  return __builtin_amdgcn_mfma_f32_16x16x32_bf16(
      __builtin_bit_cast(bf16x8, a), __builtin_bit_cast(bf16x8, b), c, 0, 0, 0);
}

__device__ __forceinline__ void gload_lds16(void* lds, const void* g) {
  __builtin_amdgcn_global_load_lds(
      (__attribute__((address_space(1))) void*)g,
      (__attribute__((address_space(3))) void*)lds, 16, 0, 0);
}

// bijective XCD-aware block swizzle (m204)
__device__ __forceinline__ int xcd_swizzle(int orig, int nwg) {
  const int q8 = nwg >> 3, r8 = nwg & 7, xcd = orig & 7;
  return (xcd < r8 ? xcd * (q8 + 1) : r8 * (q8 + 1) + (xcd - r8) * q8) + (orig >> 3);
}

// ---------------- f32 -> bf16 convert (weights) ----------------
__global__ __launch_bounds__(256) void cvt_f2b_kernel(const float* __restrict__ in,
                                                      u16* __restrict__ out) {
  const size_t i = ((size_t)blockIdx.x * 256 + threadIdx.x) * 4;
  const float4 v = *(const float4*)(in + i);
  ushort4 o;
  o.x = f2bits(v.x); o.y = f2bits(v.y); o.z = f2bits(v.z); o.w = f2bits(v.w);
  *(ushort4*)(out + i) = o;
}

// ---------------- LayerNorm (EPS=0 per source bug), f32 in -> bf16 out ----------------
__global__ __launch_bounds__(256) void ln_kernel(const float* __restrict__ in,
                                                 const float* __restrict__ w,
                                                 u16* __restrict__ out) {
  const int row = blockIdx.x;
  const int t = threadIdx.x;
  const float4 v = ((const float4*)(in + (size_t)row * 1024))[t];
  float s = v.x + v.y + v.z + v.w;
#pragma unroll
  for (int m = 1; m < 64; m <<= 1) s += __shfl_xor(s, m);
  __shared__ float red1[4], red2[4];
  const int l = t & 63, wv = t >> 6;
  if (l == 0) red1[wv] = s;
  __syncthreads();
  const float mean = (red1[0] + red1[1] + red1[2] + red1[3]) * (1.0f / 1024.0f);
  const float d0 = v.x - mean, d1 = v.y - mean, d2 = v.z - mean, d3 = v.w - mean;
  float q = d0 * d0 + d1 * d1 + d2 * d2 + d3 * d3;
#pragma unroll
  for (int m = 1; m < 64; m <<= 1) q += __shfl_xor(q, m);
  if (l == 0) red2[wv] = q;
  __syncthreads();
  const float rs = rsqrtf((red2[0] + red2[1] + red2[2] + red2[3]) * (1.0f / 1024.0f));
  const float4 wv4 = ((const float4*)w)[t];
  ushort4 o;
  o.x = f2bits(d0 * rs * wv4.x);
  o.y = f2bits(d1 * rs * wv4.y);
  o.z = f2bits(d2 * rs * wv4.z);
  o.w = f2bits(d3 * rs * wv4.w);
  *(ushort4*)(out + (size_t)row * 1024 + t * 4) = o;
}

// ======== GEMM 256x256 tile, BK=64, 8 waves (2Mx4N), 2-phase dbuf =================
// C[m,n] = sum_k A[m,k]*B[n,k]. Swizzle: LDS(r,s) = G(r, s^(r&7)) (16B slots).
// EPI: 0 = bf16 out; 1 = f32 out + residual; 2 = exact GELU -> bf16 out.
template <int EPI>
__global__ __launch_bounds__(512) void gemm256(const u16* __restrict__ A,
                                               const u16* __restrict__ B,
                                               const float* __restrict__ res,
                                               void* __restrict__ outp,
                                               int N, int K, int gx) {
  __shared__ u16 sm[2][2][256 * 64];   // [buf][A/B][row][col] = 128 KB
  const int tid = threadIdx.x;
  const int l = tid & 63, w = tid >> 6;
  const int wr = w >> 2, wc = w & 3;
  const int lrow = l & 15, lg = l >> 4;
  const int wg = xcd_swizzle(blockIdx.x, gridDim.x);
  const int bn = wg % gx, bm = wg / gx;
  const int srow = tid >> 3;                       // 0..63
  const int gslot = (tid & 7) ^ (srow & 7);        // inverse-swizzled source slot
  const u16* Ag = A + (size_t)(bm * 256 + srow) * K + gslot * 8;
  const u16* Bg = B + (size_t)(bn * 256 + srow) * K + gslot * 8;
  f32x4 acc[8][4] = {};

#define STAGE256(buf, kt)                                                     \
  {                                                                           \
    _Pragma("unroll") for (int qq = 0; qq < 4; ++qq)                          \
        gload_lds16(&sm[buf][0][qq * 4096 + tid * 8], Ag + (size_t)(qq * 64) * K + (kt)); \
    _Pragma("unroll") for (int qq = 0; qq < 4; ++qq)                          \
        gload_lds16(&sm[buf][1][qq * 4096 + tid * 8], Bg + (size_t)(qq * 64) * K + (kt)); \
  }

  STAGE256(0, 0);
  __syncthreads();
  const int NT = K >> 6;
  int cur = 0;
  for (int t = 0; t < NT; ++t) {
    if (t + 1 < NT) STAGE256(cur ^ 1, (t + 1) << 6);
    const u16* As_ = &sm[cur][0][0];
    const u16* Bs_ = &sm[cur][1][0];
    u16x8 b[2][4];
#pragma unroll
    for (int ks = 0; ks < 2; ++ks)
#pragma unroll
      for (int j = 0; j < 4; ++j)
        b[ks][j] = *(const u16x8*)&Bs_[(wc * 64 + j * 16 + lrow) * 64 +
                                       ((ks * 4 + lg) ^ (lrow & 7)) * 8];
#pragma unroll
    for (int i = 0; i < 8; ++i) {
      const int arow = (wr * 128 + i * 16 + lrow) * 64;
      u16x8 a0 = *(const u16x8*)&As_[arow + ((0 + lg) ^ (lrow & 7)) * 8];
      u16x8 a1 = *(const u16x8*)&As_[arow + ((4 + lg) ^ (lrow & 7)) * 8];
      __builtin_amdgcn_s_setprio(1);
#pragma unroll
      for (int j = 0; j < 4; ++j) {
        acc[i][j] = mfma16(a0, b[0][j], acc[i][j]);
        acc[i][j] = mfma16(a1, b[1][j], acc[i][j]);
      }
      __builtin_amdgcn_s_setprio(0);
    }
    __syncthreads();
    cur ^= 1;
  }
#pragma unroll
  for (int i = 0; i < 8; ++i)
#pragma unroll
    for (int j = 0; j < 4; ++j) {
      const int col = bn * 256 + wc * 64 + j * 16 + lrow;
#pragma unroll
      for (int r = 0; r < 4; ++r) {
        const int row = bm * 256 + wr * 128 + i * 16 + lg * 4 + r;
        const size_t idx = (size_t)row * N + col;
        float v = acc[i][j][r];
        if (EPI == 0) {
          ((u16*)outp)[idx] = f2bits(v);
        } else if (EPI == 1) {
          ((float*)outp)[idx] = res[idx] + v;
        } else {
          float g = 0.5f * v * (1.0f + erff(v * 0.70710678118654752f));
          ((u16*)outp)[idx] = f2bits(g);
        }
      }
    }
}

// ======== GEMM 128x128 tile, BK=64, 4 waves (2x2), 2-phase dbuf (thin N) ==========
template <int EPI>
__global__ __launch_bounds__(256) void gemm128(const u16* __restrict__ A,
                                               const u16* __restrict__ B,
                                               const float* __restrict__ res,
                                               void* __restrict__ outp,
                                               int N, int K, int gx) {
  __shared__ u16 sm[2][2][128 * 64];   // 64 KB
  const int tid = threadIdx.x;
  const int l = tid & 63, w = tid >> 6;
  const int wr = w >> 1, wc = w & 1;
  const int lrow = l & 15, lg = l >> 4;
  const int wg = xcd_swizzle(blockIdx.x, gridDim.x);
  const int bn = wg % gx, bm = wg / gx;
  const int srow = tid >> 3;                  // 0..31
  const int gslot = (tid & 7) ^ (srow & 7);
  const u16* Ag = A + (size_t)(bm * 128 + srow) * K + gslot * 8;
  const u16* Bg = B + (size_t)(bn * 128 + srow) * K + gslot * 8;
  f32x4 acc[4][4] = {};

#define STAGE128(buf, kt)                                                     \
  {                                                                           \
    _Pragma("unroll") for (int qq = 0; qq < 4; ++qq)                          \
        gload_lds16(&sm[buf][0][qq * 2048 + tid * 8], Ag + (size_t)(qq * 32) * K + (kt)); \
    _Pragma("unroll") for (int qq = 0; qq < 4; ++qq)                          \
        gload_lds16(&sm[buf][1][qq * 2048 + tid * 8], Bg + (size_t)(qq * 32) * K + (kt)); \
  }

  STAGE128(0, 0);
  __syncthreads();
  const int NT = K >> 6;
  int cur = 0;
  for (int t = 0; t < NT; ++t) {
    if (t + 1 < NT) STAGE128(cur ^ 1, (t + 1) << 6);
    const u16* As_ = &sm[cur][0][0];
    const u16* Bs_ = &sm[cur][1][0];
    u16x8 b[2][4];
#pragma unroll
    for (int ks = 0; ks < 2; ++ks)
#pragma unroll
      for (int j = 0; j < 4; ++j)
        b[ks][j] = *(const u16x8*)&Bs_[(wc * 64 + j * 16 + lrow) * 64 +
                                       ((ks * 4 + lg) ^ (lrow & 7)) * 8];
#pragma unroll
    for (int i = 0; i < 4; ++i) {
      const int arow = (wr * 64 + i * 16 + lrow) * 64;
      u16x8 a0 = *(const u16x8*)&As_[arow + ((0 + lg) ^ (lrow & 7)) * 8];
      u16x8 a1 = *(const u16x8*)&As_[arow + ((4 + lg) ^ (lrow & 7)) * 8];
      __builtin_amdgcn_s_setprio(1);
#pragma unroll
      for (int j = 0; j < 4; ++j) {
        acc[i][j] = mfma16(a0, b[0][j], acc[i][j]);
        acc[i][j] = mfma16(a1, b[1][j], acc[i][j]);
      }
      __builtin_amdgcn_s_setprio(0);
    }
    __syncthreads();
    cur ^= 1;
  }
#pragma unroll
  for (int i = 0; i < 4; ++i)
#pragma unroll
    for (int j = 0; j < 4; ++j) {
      const int col = bn * 128 + wc * 64 + j * 16 + lrow;
#pragma unroll
      for (int r = 0; r < 4; ++r) {
        const int row = bm * 128 + wr * 64 + i * 16 + lg * 4 + r;
        const size_t idx = (size_t)row * N + col;
        float v = acc[i][j][r];
        if (EPI == 0) {
          ((u16*)outp)[idx] = f2bits(v);
        } else if (EPI == 1) {
          ((float*)outp)[idx] = res[idx] + v;
        } else {
          float g = 0.5f * v * (1.0f + erff(v * 0.70710678118654752f));
          ((u16*)outp)[idx] = f2bits(g);
        }
      }
    }
}

// ---------------- Flash attention (all-true mask), bf16 in/out --------------------
// K staged via pre-swizzled source (LDS(r,s)=G(r,s^(r&7)), reads XOR back -> 2-way);
// Vt/Ps padded to 72 u16 rows (144B, 16B-aligned).
__global__ __launch_bounds__(256) void attn_kernel(const u16* __restrict__ qb,
                                                   const u16* __restrict__ kb,
                                                   const u16* __restrict__ vb,
                                                   u16* __restrict__ ob,
                                                   int qs, int kstr, int vs, int os,
                                                   int H_, int M, float scale) {
  __shared__ u16 Ks[64 * 64];        // [m][d] slot-swizzled
  __shared__ u16 Vt[64 * 72];        // [d][m] padded
  __shared__ u16 Ps[4][16 * 72];     // per-wave P[q][m] padded
  const int tid = threadIdx.x;
  const int l = tid & 63, w = tid >> 6;
  const int lrow = l & 15, lg = l >> 4;
  const int bh = blockIdx.y, qt = blockIdx.x;
  const int b = bh / H_, h = bh % H_;
  const u16* qp = qb + (size_t)b * 1024 * qs + h * 64;
  const u16* kp = kb + (size_t)b * M * kstr + h * 64;
  const u16* vp = vb + (size_t)b * M * vs + h * 64;
  u16x8 aq[2];
  {
    const u16* qrow = qp + (size_t)(qt * 64 + w * 16 + lrow) * qs;
#pragma unroll
    for (int ksI = 0; ksI < 2; ++ksI) {
      u16x8 tq = *(const u16x8*)(qrow + ksI * 32 + lg * 8);
#pragma unroll
      for (int j = 0; j < 8; ++j) tq[j] = f2bits(bits2f(tq[j]) * scale);
      aq[ksI] = tq;
    }
  }
  f32x4 oacc[4] = {};
  float mrow[4], lsum[4];
#pragma unroll
  for (int r = 0; r < 4; ++r) { mrow[r] = -3.0e38f; lsum[r] = 0.0f; }
  const int srow = tid >> 3;
  const int kslot = ((tid & 7) ^ (srow & 7)) * 8;   // swizzled source col for K
  const int scol = (tid & 7) * 8;                   // linear col for V
  for (int mt = 0; mt < M; mt += 64) {
    gload_lds16(&Ks[tid * 8],        kp + (size_t)(mt + srow) * kstr + kslot);
    gload_lds16(&Ks[2048 + tid * 8], kp + (size_t)(mt + 32 + srow) * kstr + kslot);
#pragma unroll
    for (int ii = 0; ii < 2; ++ii) {     // V transpose through registers
      const int r0 = srow + ii * 32;
      u16x8 tv = *(const u16x8*)(vp + (size_t)(mt + r0) * vs + scol);
#pragma unroll
      for (int j = 0; j < 8; ++j) Vt[(scol + j) * 72 + r0] = tv[j];
    }
    __syncthreads();
    f32x4 sacc[4] = {};
#pragma unroll
    for (int nt = 0; nt < 4; ++nt)
#pragma unroll
      for (int ksI = 0; ksI < 2; ++ksI) {
        u16x8 bk = *(const u16x8*)&Ks[(nt * 16 + lrow) * 64 +
                                      ((ksI * 4 + lg) ^ (lrow & 7)) * 8];
        sacc[nt] = mfma16(aq[ksI], bk, sacc[nt]);
      }
    float alpha[4];
#pragma unroll
    for (int r = 0; r < 4; ++r) {
      float pm = fmaxf(fmaxf(sacc[0][r], sacc[1][r]), fmaxf(sacc[2][r], sacc[3][r]));
      pm = fmaxf(pm, __shfl_xor(pm, 1));
      pm = fmaxf(pm, __shfl_xor(pm, 2));
      pm = fmaxf(pm, __shfl_xor(pm, 4));
      pm = fmaxf(pm, __shfl_xor(pm, 8));
      const float nm = fmaxf(mrow[r], pm);
      alpha[r] = __expf(mrow[r] - nm);
      mrow[r] = nm;
    }
    float rsum[4] = {0.f, 0.f, 0.f, 0.f};
#pragma unroll
    for (int nt = 0; nt < 4; ++nt)
#pragma unroll
      for (int r = 0; r < 4; ++r) {
        const float p = __expf(sacc[nt][r] - mrow[r]);
        sacc[nt][r] = p;
        rsum[r] += p;
      }
#pragma unroll
    for (int r = 0; r < 4; ++r) {
      float rsv = rsum[r];
      rsv += __shfl_xor(rsv, 1); rsv += __shfl_xor(rsv, 2);
      rsv += __shfl_xor(rsv, 4); rsv += __shfl_xor(rsv, 8);
      lsum[r] = lsum[r] * alpha[r] + rsv;
    }
#pragma unroll
    for (int nt = 0; nt < 4; ++nt)
#pragma unroll
      for (int r = 0; r < 4; ++r)
        Ps[w][(lg * 4 + r) * 72 + nt * 16 + lrow] = f2bits(sacc[nt][r]);
#pragma unroll
    for (int nt = 0; nt < 4; ++nt)
#pragma unroll
      for (int r = 0; r < 4; ++r)
        oacc[nt][r] *= alpha[r];
    u16x8 pa[2];
#pragma unroll
    for (int ksI = 0; ksI < 2; ++ksI)
      pa[ksI] = *(const u16x8*)&Ps[w][lrow * 72 + ksI * 32 + lg * 8];
#pragma unroll
    for (int nt = 0; nt < 4; ++nt)
#pragma unroll
      for (int ksI = 0; ksI < 2; ++ksI) {
        u16x8 bv = *(const u16x8*)&Vt[(nt * 16 + lrow) * 72 + ksI * 32 + lg * 8];
        oacc[nt] = mfma16(pa[ksI], bv, oacc[nt]);
      }
    __syncthreads();
  }
#pragma unroll
  for (int nt = 0; nt < 4; ++nt)
#pragma unroll
    for (int r = 0; r < 4; ++r) {
      const int row = qt * 64 + w * 16 + lg * 4 + r;
      const float v = oacc[nt][r] / lsum[r];
      ob[((size_t)b * 1024 + row) * os + h * 64 + nt * 16 + lrow] = f2bits(v);
    }
}

// ------------------------------- driver -------------------------------------------
extern "C" void kernel_launch(void* const* d_in, const int* in_sizes, int n_in,
                              void* d_out, int out_size, void* d_ws, size_t ws_size,
                              hipStream_t stream) {
  (void)in_sizes; (void)n_in; (void)out_size; (void)ws_size;
  const float* x    = (const float*)d_in[0];
  const float* ctx  = (const float*)d_in[1];
  const float* wqkv = (const float*)d_in[2];
  const float* wsa  = (const float*)d_in[3];
  const float* wq   = (const float*)d_in[4];
  const float* wkv  = (const float*)d_in[5];
  const float* wxa  = (const float*)d_in[6];
  const float* wm1  = (const float*)d_in[7];
  const float* wm2  = (const float*)d_in[8];
  const float* ln1  = (const float*)d_in[9];
  const float* lnq  = (const float*)d_in[10];
  const float* lnc  = (const float*)d_in[11];
  const float* ln2  = (const float*)d_in[12];
  float* out = (float*)d_out;
  char* ws = (char*)d_ws;
  const size_t MB = 1024 * 1024;
  // Arena (72MB peak), lifetime-aliased as round 1.
  u16*   wscr  = (u16*)(ws);
  u16*   Xn    = (u16*)(ws + 8 * MB);
  u16*   qkv   = (u16*)(ws + 16 * MB);
  u16*   attnb = (u16*)(ws + 48 * MB);
  float* Xf    = (float*)(ws + 56 * MB);
  u16*   Yn    = Xn;
  u16*   Cn    = (u16*)(ws + 16 * MB);
  u16*   qx    = attnb;
  u16*   kvx   = (u16*)(ws + 24 * MB);
  u16*   xatt  = (u16*)(ws + 40 * MB);
  u16*   Zn    = Xn;
  u16*   h1    = qkv;

  const dim3 blk(256), blk5(512);
  // self-attention branch
  ln_kernel<<<4096, blk, 0, stream>>>(x, ln1, Xn);
  cvt_f2b_kernel<<<3 * 1024, blk, 0, stream>>>(wqkv, wscr);
  gemm256<0><<<192, blk5, 0, stream>>>(Xn, wscr, nullptr, qkv, 3072, 1024, 12);
  attn_kernel<<<dim3(16, 64), blk, 0, stream>>>(qkv, qkv + 1024, qkv + 2048, attnb,
                                                3072, 3072, 3072, 1024, 16, 1024, 0.125f);
  cvt_f2b_kernel<<<1024, blk, 0, stream>>>(wsa, wscr);
  gemm128<1><<<256, blk, 0, stream>>>(attnb, wscr, x, Xf, 1024, 1024, 8);
  // cross-attention branch
  ln_kernel<<<4096, blk, 0, stream>>>(Xf, lnq, Yn);
  ln_kernel<<<4096, blk, 0, stream>>>(ctx, lnc, Cn);
  cvt_f2b_kernel<<<1024, blk, 0, stream>>>(wq, wscr);
  gemm128<0><<<256, blk, 0, stream>>>(Yn, wscr, nullptr, qx, 1024, 1024, 8);
  cvt_f2b_kernel<<<2 * 1024, blk, 0, stream>>>(wkv, wscr);
  gemm256<0><<<128, blk5, 0, stream>>>(Cn, wscr, nullptr, kvx, 2048, 1024, 8);
  attn_kernel<<<dim3(16, 64), blk, 0, stream>>>(qx, kvx, kvx + 1024, xatt,
                                                1024, 2048, 2048, 1024, 16, 1024, 0.125f);
  cvt_f2b_kernel<<<1024, blk, 0, stream>>>(wxa, wscr);
  gemm128<1><<<256, blk, 0, stream>>>(xatt, wscr, Xf, out, 1024, 1024, 8);
  // MLP (Y == out; final GEMM does in-place residual)
  ln_kernel<<<4096, blk, 0, stream>>>(out, ln2, Zn);
  cvt_f2b_kernel<<<4 * 1024, blk, 0, stream>>>(wm1, wscr);
  gemm256<2><<<256, blk5, 0, stream>>>(Zn, wscr, nullptr, h1, 4096, 1024, 16);
  cvt_f2b_kernel<<<4 * 1024, blk, 0, stream>>>(wm2, wscr);
  gemm128<1><<<256, blk, 0, stream>>>(h1, wscr, out, out, 1024, 4096, 8);
}

// Round 7
// 501.236 us; speedup vs baseline: 1.4228x; 1.1495x over previous
//
#include <hip/hip_runtime.h>
#include <hip/hip_bf16.h>

// DecoderBlock on MI355X (gfx950), round 6 = round 5 resubmitted (broker timeout,
// never benched). vs round 4 (576us): attention rewritten with swapped QK^T (S^T
// lane-local rows: per-lane scalar softmax state, 4 shfls/tile instead of 32),
// vectorized P-store (4x ds_write_b64, stride-72), and XOR-slot Vt layout
// (conflict-free transpose writes AND b128 reads). GEMMs unchanged (validated r4).
// B=4, L=M=1024, DIM=1024, H=16, d=64, HID=4096. All GEMMs A[4096,K] @ W[N,K]^T.

typedef unsigned short u16;
typedef unsigned short u16x8 __attribute__((ext_vector_type(8)));
typedef __bf16 bf16x8 __attribute__((ext_vector_type(8)));
typedef float f32x4 __attribute__((ext_vector_type(4)));

__device__ __forceinline__ u16 f2bits(float f) {
  __hip_bfloat16 h = __float2bfloat16(f);
  return __builtin_bit_cast(u16, h);
}
__device__ __forceinline__ float bits2f(u16 b) {
  return __uint_as_float(((unsigned)b) << 16);
}

__device__ __forceinline__ f32x4 mfma16(u16x8 a, u16x8 b, f32x4 c) {
  return __builtin_amdgcn_mfma_f32_16x16x32_bf16(
      __builtin_bit_cast(bf16x8, a), __builtin_bit_cast(bf16x8, b), c, 0, 0, 0);
}

__device__ __forceinline__ void gload_lds16(void* lds, const void* g) {
  __builtin_amdgcn_global_load_lds(
      (__attribute__((address_space(1))) void*)g,
      (__attribute__((address_space(3))) void*)lds, 16, 0, 0);
}

// bijective XCD-aware block swizzle (m204)
__device__ __forceinline__ int xcd_swizzle(int orig, int nwg) {
  const int q8 = nwg >> 3, r8 = nwg & 7, xcd = orig & 7;
  return (xcd < r8 ? xcd * (q8 + 1) : r8 * (q8 + 1) + (xcd - r8) * q8) + (orig >> 3);
}

// ---------------- f32 -> bf16 convert (weights) ----------------
__global__ __launch_bounds__(256) void cvt_f2b_kernel(const float* __restrict__ in,
                                                      u16* __restrict__ out) {
  const size_t i = ((size_t)blockIdx.x * 256 + threadIdx.x) * 4;
  const float4 v = *(const float4*)(in + i);
  ushort4 o;
  o.x = f2bits(v.x); o.y = f2bits(v.y); o.z = f2bits(v.z); o.w = f2bits(v.w);
  *(ushort4*)(out + i) = o;
}

// ---------------- LayerNorm (EPS=0 per source bug), f32 in -> bf16 out ----------------
__global__ __launch_bounds__(256) void ln_kernel(const float* __restrict__ in,
                                                 const float* __restrict__ w,
                                                 u16* __restrict__ out) {
  const int row = blockIdx.x;
  const int t = threadIdx.x;
  const float4 v = ((const float4*)(in + (size_t)row * 1024))[t];
  float s = v.x + v.y + v.z + v.w;
#pragma unroll
  for (int m = 1; m < 64; m <<= 1) s += __shfl_xor(s, m);
  __shared__ float red1[4], red2[4];
  const int l = t & 63, wv = t >> 6;
  if (l == 0) red1[wv] = s;
  __syncthreads();
  const float mean = (red1[0] + red1[1] + red1[2] + red1[3]) * (1.0f / 1024.0f);
  const float d0 = v.x - mean, d1 = v.y - mean, d2 = v.z - mean, d3 = v.w - mean;
  float q = d0 * d0 + d1 * d1 + d2 * d2 + d3 * d3;
#pragma unroll
  for (int m = 1; m < 64; m <<= 1) q += __shfl_xor(q, m);
  if (l == 0) red2[wv] = q;
  __syncthreads();
  const float rs = rsqrtf((red2[0] + red2[1] + red2[2] + red2[3]) * (1.0f / 1024.0f));
  const float4 wv4 = ((const float4*)w)[t];
  ushort4 o;
  o.x = f2bits(d0 * rs * wv4.x);
  o.y = f2bits(d1 * rs * wv4.y);
  o.z = f2bits(d2 * rs * wv4.z);
  o.w = f2bits(d3 * rs * wv4.w);
  *(ushort4*)(out + (size_t)row * 1024 + t * 4) = o;
}

// ======== GEMM 256x256 tile, BK=64, 8 waves (2Mx4N), 2-phase dbuf =================
template <int EPI>
__global__ __launch_bounds__(512) void gemm256(const u16* __restrict__ A,
                                               const u16* __restrict__ B,
                                               const float* __restrict__ res,
                                               void* __restrict__ outp,
                                               int N, int K, int gx) {
  __shared__ u16 sm[2][2][256 * 64];   // [buf][A/B][row][col] = 128 KB
  const int tid = threadIdx.x;
  const int l = tid & 63, w = tid >> 6;
  const int wr = w >> 2, wc = w & 3;
  const int lrow = l & 15, lg = l >> 4;
  const int wg = xcd_swizzle(blockIdx.x, gridDim.x);
  const int bn = wg % gx, bm = wg / gx;
  const int srow = tid >> 3;                       // 0..63
  const int gslot = (tid & 7) ^ (srow & 7);        // inverse-swizzled source slot
  const u16* Ag = A + (size_t)(bm * 256 + srow) * K + gslot * 8;
  const u16* Bg = B + (size_t)(bn * 256 + srow) * K + gslot * 8;
  f32x4 acc[8][4] = {};

#define STAGE256(buf, kt)                                                     \
  {                                                                           \
    _Pragma("unroll") for (int qq = 0; qq < 4; ++qq)                          \
        gload_lds16(&sm[buf][0][qq * 4096 + tid * 8], Ag + (size_t)(qq * 64) * K + (kt)); \
    _Pragma("unroll") for (int qq = 0; qq < 4; ++qq)                          \
        gload_lds16(&sm[buf][1][qq * 4096 + tid * 8], Bg + (size_t)(qq * 64) * K + (kt)); \
  }

  STAGE256(0, 0);
  __syncthreads();
  const int NT = K >> 6;
  int cur = 0;
  for (int t = 0; t < NT; ++t) {
    if (t + 1 < NT) STAGE256(cur ^ 1, (t + 1) << 6);
    const u16* As_ = &sm[cur][0][0];
    const u16* Bs_ = &sm[cur][1][0];
    u16x8 b[2][4];
#pragma unroll
    for (int ks = 0; ks < 2; ++ks)
#pragma unroll
      for (int j = 0; j < 4; ++j)
        b[ks][j] = *(const u16x8*)&Bs_[(wc * 64 + j * 16 + lrow) * 64 +
                                       ((ks * 4 + lg) ^ (lrow & 7)) * 8];
#pragma unroll
    for (int i = 0; i < 8; ++i) {
      const int arow = (wr * 128 + i * 16 + lrow) * 64;
      u16x8 a0 = *(const u16x8*)&As_[arow + ((0 + lg) ^ (lrow & 7)) * 8];
      u16x8 a1 = *(const u16x8*)&As_[arow + ((4 + lg) ^ (lrow & 7)) * 8];
      __builtin_amdgcn_s_setprio(1);
#pragma unroll
      for (int j = 0; j < 4; ++j) {
        acc[i][j] = mfma16(a0, b[0][j], acc[i][j]);
        acc[i][j] = mfma16(a1, b[1][j], acc[i][j]);
      }
      __builtin_amdgcn_s_setprio(0);
    }
    __syncthreads();
    cur ^= 1;
  }
#pragma unroll
  for (int i = 0; i < 8; ++i)
#pragma unroll
    for (int j = 0; j < 4; ++j) {
      const int col = bn * 256 + wc * 64 + j * 16 + lrow;
#pragma unroll
      for (int r = 0; r < 4; ++r) {
        const int row = bm * 256 + wr * 128 + i * 16 + lg * 4 + r;
        const size_t idx = (size_t)row * N + col;
        float v = acc[i][j][r];
        if (EPI == 0) {
          ((u16*)outp)[idx] = f2bits(v);
        } else if (EPI == 1) {
          ((float*)outp)[idx] = res[idx] + v;
        } else {
          float g = 0.5f * v * (1.0f + erff(v * 0.70710678118654752f));
          ((u16*)outp)[idx] = f2bits(g);
        }
      }
    }
}

// ======== GEMM 128x128 tile, BK=64, 4 waves (2x2), 2-phase dbuf (thin N) ==========
template <int EPI>
__global__ __launch_bounds__(256) void gemm128(const u16* __restrict__ A,
                                               const u16* __restrict__ B,
                                               const float* __restrict__ res,
                                               void* __restrict__ outp,
                                               int N, int K, int gx) {
  __shared__ u16 sm[2][2][128 * 64];   // 64 KB
  const int tid = threadIdx.x;
  const int l = tid & 63, w = tid >> 6;
  const int wr = w >> 1, wc = w & 1;
  const int lrow = l & 15, lg = l >> 4;
  const int wg = xcd_swizzle(blockIdx.x, gridDim.x);
  const int bn = wg % gx, bm = wg / gx;
  const int srow = tid >> 3;                  // 0..31
  const int gslot = (tid & 7) ^ (srow & 7);
  const u16* Ag = A + (size_t)(bm * 128 + srow) * K + gslot * 8;
  const u16* Bg = B + (size_t)(bn * 128 + srow) * K + gslot * 8;
  f32x4 acc[4][4] = {};

#define STAGE128(buf, kt)                                                     \
  {                                                                           \
    _Pragma("unroll") for (int qq = 0; qq < 4; ++qq)                          \
        gload_lds16(&sm[buf][0][qq * 2048 + tid * 8], Ag + (size_t)(qq * 32) * K + (kt)); \
    _Pragma("unroll") for (int qq = 0; qq < 4; ++qq)                          \
        gload_lds16(&sm[buf][1][qq * 2048 + tid * 8], Bg + (size_t)(qq * 32) * K + (kt)); \
  }

  STAGE128(0, 0);
  __syncthreads();
  const int NT = K >> 6;
  int cur = 0;
  for (int t = 0; t < NT; ++t) {
    if (t + 1 < NT) STAGE128(cur ^ 1, (t + 1) << 6);
    const u16* As_ = &sm[cur][0][0];
    const u16* Bs_ = &sm[cur][1][0];
    u16x8 b[2][4];
#pragma unroll
    for (int ks = 0; ks < 2; ++ks)
#pragma unroll
      for (int j = 0; j < 4; ++j)
        b[ks][j] = *(const u16x8*)&Bs_[(wc * 64 + j * 16 + lrow) * 64 +
                                       ((ks * 4 + lg) ^ (lrow & 7)) * 8];
#pragma unroll
    for (int i = 0; i < 4; ++i) {
      const int arow = (wr * 64 + i * 16 + lrow) * 64;
      u16x8 a0 = *(const u16x8*)&As_[arow + ((0 + lg) ^ (lrow & 7)) * 8];
      u16x8 a1 = *(const u16x8*)&As_[arow + ((4 + lg) ^ (lrow & 7)) * 8];
      __builtin_amdgcn_s_setprio(1);
#pragma unroll
      for (int j = 0; j < 4; ++j) {
        acc[i][j] = mfma16(a0, b[0][j], acc[i][j]);
        acc[i][j] = mfma16(a1, b[1][j], acc[i][j]);
      }
      __builtin_amdgcn_s_setprio(0);
    }
    __syncthreads();
    cur ^= 1;
  }
#pragma unroll
  for (int i = 0; i < 4; ++i)
#pragma unroll
    for (int j = 0; j < 4; ++j) {
      const int col = bn * 128 + wc * 64 + j * 16 + lrow;
#pragma unroll
      for (int r = 0; r < 4; ++r) {
        const int row = bm * 128 + wr * 64 + i * 16 + lg * 4 + r;
        const size_t idx = (size_t)row * N + col;
        float v = acc[i][j][r];
        if (EPI == 0) {
          ((u16*)outp)[idx] = f2bits(v);
        } else if (EPI == 1) {
          ((float*)outp)[idx] = res[idx] + v;
        } else {
          float g = 0.5f * v * (1.0f + erff(v * 0.70710678118654752f));
          ((u16*)outp)[idx] = f2bits(g);
        }
      }
    }
}

// ---------------- Flash attention v2: swapped QK^T, bf16 in/out ------------------
// mfma(K,Q) -> S^T: lane (lrow,lg) holds S[k=km*16+lg*4+r][q=lrow] -> per-lane
// scalar softmax state, 4 shfls/tile. P stored as 4x ds_write_b64 rows (stride 72).
// Vt XOR-slot layout: addr(d,r) = d*64 + (((r>>3)^((d>>3)+(d&7)))&7)*8 + (r&7):
// conflict-free for scatter writes and b128 reads. O rescale via 4-shfl alpha bcast.
__global__ __launch_bounds__(256) void attn_kernel(const u16* __restrict__ qb,
                                                   const u16* __restrict__ kb,
                                                   const u16* __restrict__ vb,
                                                   u16* __restrict__ ob,
                                                   int qs, int kstr, int vs, int os,
                                                   int H_, int M, float scale) {
  __shared__ u16 Ks[64 * 64];        // [m][d] slot-swizzled
  __shared__ u16 Vt[64 * 64];        // [d][r] XOR-slot layout
  __shared__ u16 Ps[4][16 * 72];     // per-wave P[q][k], stride 72 (144B rows)
  const int tid = threadIdx.x;
  const int l = tid & 63, w = tid >> 6;
  const int lrow = l & 15, lg = l >> 4;
  const int bh = blockIdx.y, qt = blockIdx.x;
  const int b = bh / H_, h = bh % H_;
  const u16* qp = qb + (size_t)b * 1024 * qs + h * 64;
  const u16* kp = kb + (size_t)b * M * kstr + h * 64;
  const u16* vp = vb + (size_t)b * M * vs + h * 64;
  // Q fragment (B-operand: n=q=lrow, k=d=lg*8+j), pre-scaled by 1/8 (exact in bf16)
  u16x8 aq[2];
  {
    const u16* qrow = qp + (size_t)(qt * 64 + w * 16 + lrow) * qs;
#pragma unroll
    for (int ks = 0; ks < 2; ++ks) {
      u16x8 tq = *(const u16x8*)(qrow + ks * 32 + lg * 8);
#pragma unroll
      for (int j = 0; j < 8; ++j) tq[j] = f2bits(bits2f(tq[j]) * scale);
      aq[ks] = tq;
    }
  }
  f32x4 oacc[4] = {};
  float mst = -3.0e38f, lst = 0.0f;
  const int srow = tid >> 3;                        // 0..31 (block-wide)
  const int kslot = ((tid & 7) ^ (srow & 7)) * 8;   // swizzled source col for K
  const int scol = (tid & 7) * 8;                   // linear col for V rows
  for (int mt = 0; mt < M; mt += 64) {
    gload_lds16(&Ks[tid * 8],        kp + (size_t)(mt + srow) * kstr + kslot);
    gload_lds16(&Ks[2048 + tid * 8], kp + (size_t)(mt + 32 + srow) * kstr + kslot);
#pragma unroll
    for (int ii = 0; ii < 2; ++ii) {     // V transpose -> XOR-slot layout
      const int r0 = srow + ii * 32;
      u16x8 tv = *(const u16x8*)(vp + (size_t)(mt + r0) * vs + scol);
#pragma unroll
      for (int j = 0; j < 8; ++j) {
        const int d = scol + j;
        Vt[d * 64 + (((r0 >> 3) ^ ((tid & 7) + j)) & 7) * 8 + (r0 & 7)] = tv[j];
      }
    }
    __syncthreads();
    // S^T = mfma(K, Q): sacc[km][r] = S[k=km*16+lg*4+r][q=lrow]
    f32x4 sacc[4] = {};
#pragma unroll
    for (int km = 0; km < 4; ++km)
#pragma unroll
      for (int ks = 0; ks < 2; ++ks) {
        u16x8 bk = *(const u16x8*)&Ks[(km * 16 + lrow) * 64 +
                                      ((ks * 4 + lg) ^ (lrow & 7)) * 8];
        sacc[km] = mfma16(bk, aq[ks], sacc[km]);
      }
    // online softmax, per-lane scalar state for q=lrow
    float pm = fmaxf(fmaxf(fmaxf(sacc[0][0], sacc[0][1]), fmaxf(sacc[0][2], sacc[0][3])),
                     fmaxf(fmaxf(sacc[1][0], sacc[1][1]), fmaxf(sacc[1][2], sacc[1][3])));
    pm = fmaxf(pm, fmaxf(fmaxf(fmaxf(sacc[2][0], sacc[2][1]), fmaxf(sacc[2][2], sacc[2][3])),
                         fmaxf(fmaxf(sacc[3][0], sacc[3][1]), fmaxf(sacc[3][2], sacc[3][3]))));
    pm = fmaxf(pm, __shfl_xor(pm, 16));
    pm = fmaxf(pm, __shfl_xor(pm, 32));
    const float nm = fmaxf(mst, pm);
    const float alpha = __expf(mst - nm);
    mst = nm;
    float rs = 0.0f;
#pragma unroll
    for (int km = 0; km < 4; ++km)
#pragma unroll
      for (int r = 0; r < 4; ++r) {
        const float p = __expf(sacc[km][r] - nm);
        sacc[km][r] = p;
        rs += p;
      }
    rs += __shfl_xor(rs, 16);
    rs += __shfl_xor(rs, 32);
    lst = lst * alpha + rs;
    // P -> LDS: lane owns 4 consecutive k per km: one 8B write each
#pragma unroll
    for (int km = 0; km < 4; ++km) {
      uint2 pk2;
      pk2.x = (unsigned)f2bits(sacc[km][0]) | ((unsigned)f2bits(sacc[km][1]) << 16);
      pk2.y = (unsigned)f2bits(sacc[km][2]) | ((unsigned)f2bits(sacc[km][3]) << 16);
      *(uint2*)&Ps[w][lrow * 72 + km * 16 + lg * 4] = pk2;
    }
    // rescale O (O-layout q = lg*4+r; alpha lives at lane with lane&15 == q)
    float af[4];
#pragma unroll
    for (int r = 0; r < 4; ++r) af[r] = __shfl(alpha, (l & 48) | ((l >> 4) * 4 + r));
#pragma unroll
    for (int nt = 0; nt < 4; ++nt)
#pragma unroll
      for (int r = 0; r < 4; ++r) oacc[nt][r] *= af[r];
    // PV: A = P (m=q=lrow, k=ks*32+lg*8), B = Vt (n=d=nt*16+lrow)
    u16x8 pa[2];
#pragma unroll
    for (int ks = 0; ks < 2; ++ks)
      pa[ks] = *(const u16x8*)&Ps[w][lrow * 72 + ks * 32 + lg * 8];
#pragma unroll
    for (int nt = 0; nt < 4; ++nt) {
      const int d = nt * 16 + lrow;
      const int sig = ((nt * 2 + (lrow >> 3)) + (lrow & 7)) & 7;
#pragma unroll
      for (int ks = 0; ks < 2; ++ks) {
        u16x8 bv = *(const u16x8*)&Vt[d * 64 + (((ks * 4 + lg) ^ sig) & 7) * 8];
        oacc[nt] = mfma16(pa[ks], bv, oacc[nt]);
      }
    }
    __syncthreads();
  }
  // epilogue: O[q=lg*4+r][d=nt*16+lrow] / lsum[q]
  float lf[4];
#pragma unroll
  for (int r = 0; r < 4; ++r) lf[r] = __shfl(lst, (l & 48) | ((l >> 4) * 4 + r));
#pragma unroll
  for (int nt = 0; nt < 4; ++nt)
#pragma unroll
    for (int r = 0; r < 4; ++r) {
      const int row = qt * 64 + w * 16 + lg * 4 + r;
      const float v = oacc[nt][r] / lf[r];
      ob[((size_t)b * 1024 + row) * os + h * 64 + nt * 16 + lrow] = f2bits(v);
    }
}

// ------------------------------- driver -------------------------------------------
extern "C" void kernel_launch(void* const* d_in, const int* in_sizes, int n_in,
                              void* d_out, int out_size, void* d_ws, size_t ws_size,
                              hipStream_t stream) {
  (void)in_sizes; (void)n_in; (void)out_size; (void)ws_size;
  const float* x    = (const float*)d_in[0];
  const float* ctx  = (const float*)d_in[1];
  const float* wqkv = (const float*)d_in[2];
  const float* wsa  = (const float*)d_in[3];
  const float* wq   = (const float*)d_in[4];
  const float* wkv  = (const float*)d_in[5];
  const float* wxa  = (const float*)d_in[6];
  const float* wm1  = (const float*)d_in[7];
  const float* wm2  = (const float*)d_in[8];
  const float* ln1  = (const float*)d_in[9];
  const float* lnq  = (const float*)d_in[10];
  const float* lnc  = (const float*)d_in[11];
  const float* ln2  = (const float*)d_in[12];
  float* out = (float*)d_out;
  char* ws = (char*)d_ws;
  const size_t MB = 1024 * 1024;
  // Arena (72MB peak), lifetime-aliased as round 1.
  u16*   wscr  = (u16*)(ws);
  u16*   Xn    = (u16*)(ws + 8 * MB);
  u16*   qkv   = (u16*)(ws + 16 * MB);
  u16*   attnb = (u16*)(ws + 48 * MB);
  float* Xf    = (float*)(ws + 56 * MB);
  u16*   Yn    = Xn;
  u16*   Cn    = (u16*)(ws + 16 * MB);
  u16*   qx    = attnb;
  u16*   kvx   = (u16*)(ws + 24 * MB);
  u16*   xatt  = (u16*)(ws + 40 * MB);
  u16*   Zn    = Xn;
  u16*   h1    = qkv;

  const dim3 blk(256), blk5(512);
  // self-attention branch
  ln_kernel<<<4096, blk, 0, stream>>>(x, ln1, Xn);
  cvt_f2b_kernel<<<3 * 1024, blk, 0, stream>>>(wqkv, wscr);
  gemm256<0><<<192, blk5, 0, stream>>>(Xn, wscr, nullptr, qkv, 3072, 1024, 12);
  attn_kernel<<<dim3(16, 64), blk, 0, stream>>>(qkv, qkv + 1024, qkv + 2048, attnb,
                                                3072, 3072, 3072, 1024, 16, 1024, 0.125f);
  cvt_f2b_kernel<<<1024, blk, 0, stream>>>(wsa, wscr);
  gemm128<1><<<256, blk, 0, stream>>>(attnb, wscr, x, Xf, 1024, 1024, 8);
  // cross-attention branch
  ln_kernel<<<4096, blk, 0, stream>>>(Xf, lnq, Yn);
  ln_kernel<<<4096, blk, 0, stream>>>(ctx, lnc, Cn);
  cvt_f2b_kernel<<<1024, blk, 0, stream>>>(wq, wscr);
  gemm128<0><<<256, blk, 0, stream>>>(Yn, wscr, nullptr, qx, 1024, 1024, 8);
  cvt_f2b_kernel<<<2 * 1024, blk, 0, stream>>>(wkv, wscr);
  gemm256<0><<<128, blk5, 0, stream>>>(Cn, wscr, nullptr, kvx, 2048, 1024, 8);
  attn_kernel<<<dim3(16, 64), blk, 0, stream>>>(qx, kvx, kvx + 1024, xatt,
                                                1024, 2048, 2048, 1024, 16, 1024, 0.125f);
  cvt_f2b_kernel<<<1024, blk, 0, stream>>>(wxa, wscr);
  gemm128<1><<<256, blk, 0, stream>>>(xatt, wscr, Xf, out, 1024, 1024, 8);
  // MLP (Y == out; final GEMM does in-place residual)
  ln_kernel<<<4096, blk, 0, stream>>>(out, ln2, Zn);
  cvt_f2b_kernel<<<4 * 1024, blk, 0, stream>>>(wm1, wscr);
  gemm256<2><<<256, blk5, 0, stream>>>(Zn, wscr, nullptr, h1, 4096, 1024, 16);
  cvt_f2b_kernel<<<4 * 1024, blk, 0, stream>>>(wm2, wscr);
  gemm128<1><<<256, blk, 0, stream>>>(h1, wscr, out, out, 1024, 4096, 8);
}

// Round 9
// 495.288 us; speedup vs baseline: 1.4399x; 1.0120x over previous
//
#include <hip/hip_runtime.h>
#include <hip/hip_bf16.h>

// DecoderBlock on MI355X (gfx950), round 8 = round 7 resubmitted (broker timeout,
// never benched). vs round 6 (501us): all large GEMMs moved from gemm256 (128KB LDS
// -> 1 block/CU, occupancy-capped 19%, 584 TF) to validated gemm128 (64KB LDS ->
// 2 blocks/CU; co-resident blocks hide each other's barrier drains; m103: 128-tile
// beats 256-tile at 2-barrier structures). gemm256 removed. Attention unchanged.
// B=4, L=M=1024, DIM=1024, H=16, d=64, HID=4096. All GEMMs A[4096,K] @ W[N,K]^T.

typedef unsigned short u16;
typedef unsigned short u16x8 __attribute__((ext_vector_type(8)));
typedef __bf16 bf16x8 __attribute__((ext_vector_type(8)));
typedef float f32x4 __attribute__((ext_vector_type(4)));

__device__ __forceinline__ u16 f2bits(float f) {
  __hip_bfloat16 h = __float2bfloat16(f);
  return __builtin_bit_cast(u16, h);
}
__device__ __forceinline__ float bits2f(u16 b) {
  return __uint_as_float(((unsigned)b) << 16);
}

__device__ __forceinline__ f32x4 mfma16(u16x8 a, u16x8 b, f32x4 c) {
  return __builtin_amdgcn_mfma_f32_16x16x32_bf16(
      __builtin_bit_cast(bf16x8, a), __builtin_bit_cast(bf16x8, b), c, 0, 0, 0);
}

__device__ __forceinline__ void gload_lds16(void* lds, const void* g) {
  __builtin_amdgcn_global_load_lds(
      (__attribute__((address_space(1))) void*)g,
      (__attribute__((address_space(3))) void*)lds, 16, 0, 0);
}

// bijective XCD-aware block swizzle (m204)
__device__ __forceinline__ int xcd_swizzle(int orig, int nwg) {
  const int q8 = nwg >> 3, r8 = nwg & 7, xcd = orig & 7;
  return (xcd < r8 ? xcd * (q8 + 1) : r8 * (q8 + 1) + (xcd - r8) * q8) + (orig >> 3);
}

// ---------------- f32 -> bf16 convert (weights) ----------------
__global__ __launch_bounds__(256) void cvt_f2b_kernel(const float* __restrict__ in,
                                                      u16* __restrict__ out) {
  const size_t i = ((size_t)blockIdx.x * 256 + threadIdx.x) * 4;
  const float4 v = *(const float4*)(in + i);
  ushort4 o;
  o.x = f2bits(v.x); o.y = f2bits(v.y); o.z = f2bits(v.z); o.w = f2bits(v.w);
  *(ushort4*)(out + i) = o;
}

// ---------------- LayerNorm (EPS=0 per source bug), f32 in -> bf16 out ----------------
__global__ __launch_bounds__(256) void ln_kernel(const float* __restrict__ in,
                                                 const float* __restrict__ w,
                                                 u16* __restrict__ out) {
  const int row = blockIdx.x;
  const int t = threadIdx.x;
  const float4 v = ((const float4*)(in + (size_t)row * 1024))[t];
  float s = v.x + v.y + v.z + v.w;
#pragma unroll
  for (int m = 1; m < 64; m <<= 1) s += __shfl_xor(s, m);
  __shared__ float red1[4], red2[4];
  const int l = t & 63, wv = t >> 6;
  if (l == 0) red1[wv] = s;
  __syncthreads();
  const float mean = (red1[0] + red1[1] + red1[2] + red1[3]) * (1.0f / 1024.0f);
  const float d0 = v.x - mean, d1 = v.y - mean, d2 = v.z - mean, d3 = v.w - mean;
  float q = d0 * d0 + d1 * d1 + d2 * d2 + d3 * d3;
#pragma unroll
  for (int m = 1; m < 64; m <<= 1) q += __shfl_xor(q, m);
  if (l == 0) red2[wv] = q;
  __syncthreads();
  const float rs = rsqrtf((red2[0] + red2[1] + red2[2] + red2[3]) * (1.0f / 1024.0f));
  const float4 wv4 = ((const float4*)w)[t];
  ushort4 o;
  o.x = f2bits(d0 * rs * wv4.x);
  o.y = f2bits(d1 * rs * wv4.y);
  o.z = f2bits(d2 * rs * wv4.z);
  o.w = f2bits(d3 * rs * wv4.w);
  *(ushort4*)(out + (size_t)row * 1024 + t * 4) = o;
}

// ======== GEMM 128x128 tile, BK=64, 4 waves (2x2), 2-phase dbuf ==================
// 64KB LDS -> 2 blocks/CU: co-resident blocks hide each other's barrier drains.
// C[m,n] = sum_k A[m,k]*B[n,k]. Swizzle: LDS(r,s) = G(r, s^(r&7)) (16B slots).
// EPI: 0 = bf16 out; 1 = f32 out + residual; 2 = exact GELU -> bf16 out.
template <int EPI>
__global__ __launch_bounds__(256) void gemm128(const u16* __restrict__ A,
                                               const u16* __restrict__ B,
                                               const float* __restrict__ res,
                                               void* __restrict__ outp,
                                               int N, int K, int gx) {
  __shared__ u16 sm[2][2][128 * 64];   // 64 KB
  const int tid = threadIdx.x;
  const int l = tid & 63, w = tid >> 6;
  const int wr = w >> 1, wc = w & 1;
  const int lrow = l & 15, lg = l >> 4;
  const int wg = xcd_swizzle(blockIdx.x, gridDim.x);
  const int bn = wg % gx, bm = wg / gx;
  const int srow = tid >> 3;                  // 0..31
  const int gslot = (tid & 7) ^ (srow & 7);
  const u16* Ag = A + (size_t)(bm * 128 + srow) * K + gslot * 8;
  const u16* Bg = B + (size_t)(bn * 128 + srow) * K + gslot * 8;
  f32x4 acc[4][4] = {};

#define STAGE128(buf, kt)                                                     \
  {                                                                           \
    _Pragma("unroll") for (int qq = 0; qq < 4; ++qq)                          \
        gload_lds16(&sm[buf][0][qq * 2048 + tid * 8], Ag + (size_t)(qq * 32) * K + (kt)); \
    _Pragma("unroll") for (int qq = 0; qq < 4; ++qq)                          \
        gload_lds16(&sm[buf][1][qq * 2048 + tid * 8], Bg + (size_t)(qq * 32) * K + (kt)); \
  }

  STAGE128(0, 0);
  __syncthreads();
  const int NT = K >> 6;
  int cur = 0;
  for (int t = 0; t < NT; ++t) {
    if (t + 1 < NT) STAGE128(cur ^ 1, (t + 1) << 6);
    const u16* As_ = &sm[cur][0][0];
    const u16* Bs_ = &sm[cur][1][0];
    u16x8 b[2][4];
#pragma unroll
    for (int ks = 0; ks < 2; ++ks)
#pragma unroll
      for (int j = 0; j < 4; ++j)
        b[ks][j] = *(const u16x8*)&Bs_[(wc * 64 + j * 16 + lrow) * 64 +
                                       ((ks * 4 + lg) ^ (lrow & 7)) * 8];
#pragma unroll
    for (int i = 0; i < 4; ++i) {
      const int arow = (wr * 64 + i * 16 + lrow) * 64;
      u16x8 a0 = *(const u16x8*)&As_[arow + ((0 + lg) ^ (lrow & 7)) * 8];
      u16x8 a1 = *(const u16x8*)&As_[arow + ((4 + lg) ^ (lrow & 7)) * 8];
      __builtin_amdgcn_s_setprio(1);
#pragma unroll
      for (int j = 0; j < 4; ++j) {
        acc[i][j] = mfma16(a0, b[0][j], acc[i][j]);
        acc[i][j] = mfma16(a1, b[1][j], acc[i][j]);
      }
      __builtin_amdgcn_s_setprio(0);
    }
    __syncthreads();
    cur ^= 1;
  }
#pragma unroll
  for (int i = 0; i < 4; ++i)
#pragma unroll
    for (int j = 0; j < 4; ++j) {
      const int col = bn * 128 + wc * 64 + j * 16 + lrow;
#pragma unroll
      for (int r = 0; r < 4; ++r) {
        const int row = bm * 128 + wr * 64 + i * 16 + lg * 4 + r;
        const size_t idx = (size_t)row * N + col;
        float v = acc[i][j][r];
        if (EPI == 0) {
          ((u16*)outp)[idx] = f2bits(v);
        } else if (EPI == 1) {
          ((float*)outp)[idx] = res[idx] + v;
        } else {
          float g = 0.5f * v * (1.0f + erff(v * 0.70710678118654752f));
          ((u16*)outp)[idx] = f2bits(g);
        }
      }
    }
}

// ---------------- Flash attention v2: swapped QK^T, bf16 in/out ------------------
// mfma(K,Q) -> S^T: lane (lrow,lg) holds S[k=km*16+lg*4+r][q=lrow] -> per-lane
// scalar softmax state, 4 shfls/tile. P stored as 4x ds_write_b64 rows (stride 72).
// Vt XOR-slot layout: addr(d,r) = d*64 + (((r>>3)^((d>>3)+(d&7)))&7)*8 + (r&7):
// conflict-free for scatter writes and b128 reads. O rescale via 4-shfl alpha bcast.
__global__ __launch_bounds__(256) void attn_kernel(const u16* __restrict__ qb,
                                                   const u16* __restrict__ kb,
                                                   const u16* __restrict__ vb,
                                                   u16* __restrict__ ob,
                                                   int qs, int kstr, int vs, int os,
                                                   int H_, int M, float scale) {
  __shared__ u16 Ks[64 * 64];        // [m][d] slot-swizzled
  __shared__ u16 Vt[64 * 64];        // [d][r] XOR-slot layout
  __shared__ u16 Ps[4][16 * 72];     // per-wave P[q][k], stride 72 (144B rows)
  const int tid = threadIdx.x;
  const int l = tid & 63, w = tid >> 6;
  const int lrow = l & 15, lg = l >> 4;
  const int bh = blockIdx.y, qt = blockIdx.x;
  const int b = bh / H_, h = bh % H_;
  const u16* qp = qb + (size_t)b * 1024 * qs + h * 64;
  const u16* kp = kb + (size_t)b * M * kstr + h * 64;
  const u16* vp = vb + (size_t)b * M * vs + h * 64;
  // Q fragment (B-operand: n=q=lrow, k=d=lg*8+j), pre-scaled by 1/8 (exact in bf16)
  u16x8 aq[2];
  {
    const u16* qrow = qp + (size_t)(qt * 64 + w * 16 + lrow) * qs;
#pragma unroll
    for (int ks = 0; ks < 2; ++ks) {
      u16x8 tq = *(const u16x8*)(qrow + ks * 32 + lg * 8);
#pragma unroll
      for (int j = 0; j < 8; ++j) tq[j] = f2bits(bits2f(tq[j]) * scale);
      aq[ks] = tq;
    }
  }
  f32x4 oacc[4] = {};
  float mst = -3.0e38f, lst = 0.0f;
  const int srow = tid >> 3;                        // 0..31 (block-wide)
  const int kslot = ((tid & 7) ^ (srow & 7)) * 8;   // swizzled source col for K
  const int scol = (tid & 7) * 8;                   // linear col for V rows
  for (int mt = 0; mt < M; mt += 64) {
    gload_lds16(&Ks[tid * 8],        kp + (size_t)(mt + srow) * kstr + kslot);
    gload_lds16(&Ks[2048 + tid * 8], kp + (size_t)(mt + 32 + srow) * kstr + kslot);
#pragma unroll
    for (int ii = 0; ii < 2; ++ii) {     // V transpose -> XOR-slot layout
      const int r0 = srow + ii * 32;
      u16x8 tv = *(const u16x8*)(vp + (size_t)(mt + r0) * vs + scol);
#pragma unroll
      for (int j = 0; j < 8; ++j) {
        const int d = scol + j;
        Vt[d * 64 + (((r0 >> 3) ^ ((tid & 7) + j)) & 7) * 8 + (r0 & 7)] = tv[j];
      }
    }
    __syncthreads();
    // S^T = mfma(K, Q): sacc[km][r] = S[k=km*16+lg*4+r][q=lrow]
    f32x4 sacc[4] = {};
#pragma unroll
    for (int km = 0; km < 4; ++km)
#pragma unroll
      for (int ks = 0; ks < 2; ++ks) {
        u16x8 bk = *(const u16x8*)&Ks[(km * 16 + lrow) * 64 +
                                      ((ks * 4 + lg) ^ (lrow & 7)) * 8];
        sacc[km] = mfma16(bk, aq[ks], sacc[km]);
      }
    // online softmax, per-lane scalar state for q=lrow
    float pm = fmaxf(fmaxf(fmaxf(sacc[0][0], sacc[0][1]), fmaxf(sacc[0][2], sacc[0][3])),
                     fmaxf(fmaxf(sacc[1][0], sacc[1][1]), fmaxf(sacc[1][2], sacc[1][3])));
    pm = fmaxf(pm, fmaxf(fmaxf(fmaxf(sacc[2][0], sacc[2][1]), fmaxf(sacc[2][2], sacc[2][3])),
                         fmaxf(fmaxf(sacc[3][0], sacc[3][1]), fmaxf(sacc[3][2], sacc[3][3]))));
    pm = fmaxf(pm, __shfl_xor(pm, 16));
    pm = fmaxf(pm, __shfl_xor(pm, 32));
    const float nm = fmaxf(mst, pm);
    const float alpha = __expf(mst - nm);
    mst = nm;
    float rs = 0.0f;
#pragma unroll
    for (int km = 0; km < 4; ++km)
#pragma unroll
      for (int r = 0; r < 4; ++r) {
        const float p = __expf(sacc[km][r] - nm);
        sacc[km][r] = p;
        rs += p;
      }
    rs += __shfl_xor(rs, 16);
    rs += __shfl_xor(rs, 32);
    lst = lst * alpha + rs;
    // P -> LDS: lane owns 4 consecutive k per km: one 8B write each
#pragma unroll
    for (int km = 0; km < 4; ++km) {
      uint2 pk2;
      pk2.x = (unsigned)f2bits(sacc[km][0]) | ((unsigned)f2bits(sacc[km][1]) << 16);
      pk2.y = (unsigned)f2bits(sacc[km][2]) | ((unsigned)f2bits(sacc[km][3]) << 16);
      *(uint2*)&Ps[w][lrow * 72 + km * 16 + lg * 4] = pk2;
    }
    // rescale O (O-layout q = lg*4+r; alpha lives at lane with lane&15 == q)
    float af[4];
#pragma unroll
    for (int r = 0; r < 4; ++r) af[r] = __shfl(alpha, (l & 48) | ((l >> 4) * 4 + r));
#pragma unroll
    for (int nt = 0; nt < 4; ++nt)
#pragma unroll
      for (int r = 0; r < 4; ++r) oacc[nt][r] *= af[r];
    // PV: A = P (m=q=lrow, k=ks*32+lg*8), B = Vt (n=d=nt*16+lrow)
    u16x8 pa[2];
#pragma unroll
    for (int ks = 0; ks < 2; ++ks)
      pa[ks] = *(const u16x8*)&Ps[w][lrow * 72 + ks * 32 + lg * 8];
#pragma unroll
    for (int nt = 0; nt < 4; ++nt) {
      const int d = nt * 16 + lrow;
      const int sig = ((nt * 2 + (lrow >> 3)) + (lrow & 7)) & 7;
#pragma unroll
      for (int ks = 0; ks < 2; ++ks) {
        u16x8 bv = *(const u16x8*)&Vt[d * 64 + (((ks * 4 + lg) ^ sig) & 7) * 8];
        oacc[nt] = mfma16(pa[ks], bv, oacc[nt]);
      }
    }
    __syncthreads();
  }
  // epilogue: O[q=lg*4+r][d=nt*16+lrow] / lsum[q]
  float lf[4];
#pragma unroll
  for (int r = 0; r < 4; ++r) lf[r] = __shfl(lst, (l & 48) | ((l >> 4) * 4 + r));
#pragma unroll
  for (int nt = 0; nt < 4; ++nt)
#pragma unroll
    for (int r = 0; r < 4; ++r) {
      const int row = qt * 64 + w * 16 + lg * 4 + r;
      const float v = oacc[nt][r] / lf[r];
      ob[((size_t)b * 1024 + row) * os + h * 64 + nt * 16 + lrow] = f2bits(v);
    }
}

// ------------------------------- driver -------------------------------------------
extern "C" void kernel_launch(void* const* d_in, const int* in_sizes, int n_in,
                              void* d_out, int out_size, void* d_ws, size_t ws_size,
                              hipStream_t stream) {
  (void)in_sizes; (void)n_in; (void)out_size; (void)ws_size;
  const float* x    = (const float*)d_in[0];
  const float* ctx  = (const float*)d_in[1];
  const float* wqkv = (const float*)d_in[2];
  const float* wsa  = (const float*)d_in[3];
  const float* wq   = (const float*)d_in[4];
  const float* wkv  = (const float*)d_in[5];
  const float* wxa  = (const float*)d_in[6];
  const float* wm1  = (const float*)d_in[7];
  const float* wm2  = (const float*)d_in[8];
  const float* ln1  = (const float*)d_in[9];
  const float* lnq  = (const float*)d_in[10];
  const float* lnc  = (const float*)d_in[11];
  const float* ln2  = (const float*)d_in[12];
  float* out = (float*)d_out;
  char* ws = (char*)d_ws;
  const size_t MB = 1024 * 1024;
  // Arena (72MB peak), lifetime-aliased as round 1.
  u16*   wscr  = (u16*)(ws);
  u16*   Xn    = (u16*)(ws + 8 * MB);
  u16*   qkv   = (u16*)(ws + 16 * MB);
  u16*   attnb = (u16*)(ws + 48 * MB);
  float* Xf    = (float*)(ws + 56 * MB);
  u16*   Yn    = Xn;
  u16*   Cn    = (u16*)(ws + 16 * MB);
  u16*   qx    = attnb;
  u16*   kvx   = (u16*)(ws + 24 * MB);
  u16*   xatt  = (u16*)(ws + 40 * MB);
  u16*   Zn    = Xn;
  u16*   h1    = qkv;

  const dim3 blk(256);
  // self-attention branch
  ln_kernel<<<4096, blk, 0, stream>>>(x, ln1, Xn);
  cvt_f2b_kernel<<<3 * 1024, blk, 0, stream>>>(wqkv, wscr);
  gemm128<0><<<768, blk, 0, stream>>>(Xn, wscr, nullptr, qkv, 3072, 1024, 24);
  attn_kernel<<<dim3(16, 64), blk, 0, stream>>>(qkv, qkv + 1024, qkv + 2048, attnb,
                                                3072, 3072, 3072, 1024, 16, 1024, 0.125f);
  cvt_f2b_kernel<<<1024, blk, 0, stream>>>(wsa, wscr);
  gemm128<1><<<256, blk, 0, stream>>>(attnb, wscr, x, Xf, 1024, 1024, 8);
  // cross-attention branch
  ln_kernel<<<4096, blk, 0, stream>>>(Xf, lnq, Yn);
  ln_kernel<<<4096, blk, 0, stream>>>(ctx, lnc, Cn);
  cvt_f2b_kernel<<<1024, blk, 0, stream>>>(wq, wscr);
  gemm128<0><<<256, blk, 0, stream>>>(Yn, wscr, nullptr, qx, 1024, 1024, 8);
  cvt_f2b_kernel<<<2 * 1024, blk, 0, stream>>>(wkv, wscr);
  gemm128<0><<<512, blk, 0, stream>>>(Cn, wscr, nullptr, kvx, 2048, 1024, 16);
  attn_kernel<<<dim3(16, 64), blk, 0, stream>>>(qx, kvx, kvx + 1024, xatt,
                                                1024, 2048, 2048, 1024, 16, 1024, 0.125f);
  cvt_f2b_kernel<<<1024, blk, 0, stream>>>(wxa, wscr);
  gemm128<1><<<256, blk, 0, stream>>>(xatt, wscr, Xf, out, 1024, 1024, 8);
  // MLP (Y == out; final GEMM does in-place residual)
  ln_kernel<<<4096, blk, 0, stream>>>(out, ln2, Zn);
  cvt_f2b_kernel<<<4 * 1024, blk, 0, stream>>>(wm1, wscr);
  gemm128<2><<<1024, blk, 0, stream>>>(Zn, wscr, nullptr, h1, 4096, 1024, 32);
  cvt_f2b_kernel<<<4 * 1024, blk, 0, stream>>>(wm2, wscr);
  gemm128<1><<<256, blk, 0, stream>>>(h1, wscr, out, out, 1024, 4096, 8);
}